// Round 2
// baseline (243.632 us; speedup 1.0000x reference)
//
#include <hip/hip_runtime.h>
#include <stdint.h>

// RNN: h_t = tanh(x_t W_ih^T + b_ih + b_hh + h_{t-1} W_hh^T)
// out[b,t] = W_fc . h_t + b_fc ;  hidden = h_T
// B=8192, T=512, I=H=7, O=1. All tensors fp32 (reference setup_inputs dtype;
// round-1 NaN proved inputs are NOT bf16 — fp32 low halves decode as NaN bf16s).
//
// Design: 8 lanes per batch chain (lane k owns h[k]; lane 7 computes dummy 0).
// 65536 threads = 1024 waves = 1 wave per SIMD on the full chip.
// Per step: tree-reduced 7-FMA recurrent dot + hw-exp2/rcp tanh + 7x __shfl
// (ds_bpermute) broadcast. Input projection is hoisted per 8-step chunk
// (independent of h -> full ILP). x chunks register double-buffered.

#define B_TOTAL 8192
#define T_STEPS 512

__device__ __forceinline__ float tanh_fast(float a) {
    // tanh(a) = 1 - 2/(1+e^{2a});  e^{2a} = exp2(a * 2*log2(e))
    float e = __builtin_amdgcn_exp2f(a * 2.8853900817779268f);
    float r = __builtin_amdgcn_rcpf(e + 1.0f);
    return __builtin_fmaf(-2.0f, r, 1.0f);
}

__global__ __launch_bounds__(256, 1) void rnn_kernel(
    const float* __restrict__ x,    // [B, T, I]
    const float* __restrict__ Wih,  // [H, I]
    const float* __restrict__ Whh,  // [H, H]
    const float* __restrict__ bih,  // [H]
    const float* __restrict__ bhh,  // [H]
    const float* __restrict__ Wfc,  // [1, H]
    const float* __restrict__ bfc,  // [1]
    float* __restrict__ out)        // [B*T] out, then [B*H] hidden
{
    const int tid  = threadIdx.x;
    const int k    = tid & 7;                 // h-component owned by this lane
    const int b    = blockIdx.x * 32 + (tid >> 3);
    const int base = (tid & 63) & ~7;         // group base lane within wave

    // Per-lane weight rows (lane 7 -> zeros => h7 == tanh(0) == 0)
    float wih[7], whh[7];
    float bias = 0.0f;
    if (k < 7) {
        #pragma unroll
        for (int i = 0; i < 7; ++i) {
            wih[i] = Wih[k * 7 + i];
            whh[i] = Whh[k * 7 + i];
        }
        bias = bih[k] + bhh[k];
    } else {
        #pragma unroll
        for (int i = 0; i < 7; ++i) { wih[i] = 0.0f; whh[i] = 0.0f; }
    }
    float wfc[7];
    #pragma unroll
    for (int j = 0; j < 7; ++j) wfc[j] = Wfc[j];
    const float bfcv = bfc[0];

    // x row: 512*7 = 3584 floats = 14336 B (16B-aligned per row) = 896 float4
    const float4* xrow = (const float4*)(x + (size_t)b * (T_STEPS * 7));

    float h[7];
    #pragma unroll
    for (int j = 0; j < 7; ++j) h[j] = 0.0f;

    float* outp = out + (size_t)b * T_STEPS;

    float4 bufA[14], bufB[14];   // 8 steps * 7 inputs = 56 floats per chunk
    #pragma unroll
    for (int i = 0; i < 14; ++i) bufA[i] = xrow[i];

    auto process = [&](const float4 (&buf)[14], int c) {
        float xv[56];
        #pragma unroll
        for (int i = 0; i < 14; ++i) {
            xv[4 * i + 0] = buf[i].x; xv[4 * i + 1] = buf[i].y;
            xv[4 * i + 2] = buf[i].z; xv[4 * i + 3] = buf[i].w;
        }
        // Input projection for all 8 steps (independent of h -> ILP), tree-reduced
        float u[8];
        #pragma unroll
        for (int s = 0; s < 8; ++s) {
            float m0 = wih[0] * xv[s * 7 + 0];
            float m1 = wih[1] * xv[s * 7 + 1];
            float m2 = wih[2] * xv[s * 7 + 2];
            float m3 = wih[3] * xv[s * 7 + 3];
            float m4 = wih[4] * xv[s * 7 + 4];
            float m5 = wih[5] * xv[s * 7 + 5];
            float m6 = wih[6] * xv[s * 7 + 6];
            u[s] = ((m0 + m1) + (m2 + m3)) + ((m4 + m5) + (m6 + bias));
        }
        float o[8];
        #pragma unroll
        for (int s = 0; s < 8; ++s) {
            // recurrent dot, tree-reduced (critical path)
            float r0 = whh[0] * h[0];
            float r1 = whh[1] * h[1];
            float r2 = whh[2] * h[2];
            float r3 = whh[3] * h[3];
            float r4 = whh[4] * h[4];
            float r5 = whh[5] * h[5];
            float r6 = whh[6] * h[6];
            float acc = u[s] + (((r0 + r1) + (r2 + r3)) + ((r4 + r5) + r6));
            float hk = tanh_fast(acc);
            // broadcast new h across the 8-lane group (register bpermute)
            #pragma unroll
            for (int j = 0; j < 7; ++j)
                h[j] = __shfl(hk, base + j, 64);
            // output projection (off critical path; uniform within group)
            float f0 = wfc[0] * h[0];
            float f1 = wfc[1] * h[1];
            float f2 = wfc[2] * h[2];
            float f3 = wfc[3] * h[3];
            float f4 = wfc[4] * h[4];
            float f5 = wfc[5] * h[5];
            float f6 = wfc[6] * h[6];
            o[s] = ((f0 + f1) + (f2 + f3)) + ((f4 + f5) + (f6 + bfcv));
        }
        if (k == 7) {
            float4 lo = make_float4(o[0], o[1], o[2], o[3]);
            float4 hi = make_float4(o[4], o[5], o[6], o[7]);
            *(float4*)(outp + c * 8 + 0) = lo;   // c*8*4 B = 32B aligned
            *(float4*)(outp + c * 8 + 4) = hi;
        }
    };

    for (int c = 0; c < 64; c += 2) {
        #pragma unroll
        for (int i = 0; i < 14; ++i) bufB[i] = xrow[(c + 1) * 14 + i];
        process(bufA, c);
        if (c + 2 < 64) {
            #pragma unroll
            for (int i = 0; i < 14; ++i) bufA[i] = xrow[(c + 2) * 14 + i];
        }
        process(bufB, c + 1);
    }

    // hidden state h_T: [1, B, H] appended after out
    if (k < 7) {
        out[(size_t)B_TOTAL * T_STEPS + (size_t)b * 7 + k] = h[k];
    }
}

extern "C" void kernel_launch(void* const* d_in, const int* in_sizes, int n_in,
                              void* d_out, int out_size, void* d_ws, size_t ws_size,
                              hipStream_t stream) {
    const float* x   = (const float*)d_in[0];
    const float* Wih = (const float*)d_in[1];
    const float* Whh = (const float*)d_in[2];
    const float* bih = (const float*)d_in[3];
    const float* bhh = (const float*)d_in[4];
    const float* Wfc = (const float*)d_in[5];
    const float* bfc = (const float*)d_in[6];
    float* out = (float*)d_out;

    // 8192 chains * 8 lanes = 65536 threads; 256/block -> 256 blocks (1/CU)
    rnn_kernel<<<dim3(B_TOTAL / 32), dim3(256), 0, stream>>>(
        x, Wih, Whh, bih, bhh, Wfc, bfc, out);
}

// Round 3
// 224.151 us; speedup vs baseline: 1.0869x; 1.0869x over previous
//
#include <hip/hip_runtime.h>
#include <stdint.h>

// RNN: h_t = tanh(x_t W_ih^T + b_ih + b_hh + h_{t-1} W_hh^T)
// out[b,t] = W_fc . h_t + b_fc ;  hidden = h_T
// B=8192, T=512, I=H=7, O=1. fp32 I/O.
//
// 8 lanes per chain (lane k owns h-row k; lane 7 dummy). 65536 threads =
// 1024 waves = 1 wave/SIMD chip-wide. Round-2 showed the 7x ds_bpermute
// broadcast cost ~380 stall cyc/step (VALUBusy 25%). This round replaces it
// with DPP (VALU-rate cross-lane):
//   a_j = quad_perm[j](hk)         -> quadA: h_j,     quadB: h_{4+j}
//   b_j = row_half_mirror(a_j)     -> quadA: h_{4+j}, quadB: h_j
// The quad-dependent meaning is folded into a LOAD-TIME permutation of the
// weight rows (wa/wb, wfa/wfb per quad parity). No LDS, no lgkmcnt waits.

#define B_TOTAL 8192
#define T_STEPS 512

#define DPP_QUAD0 0x00   // quad_perm [0,0,0,0]
#define DPP_QUAD1 0x55   // quad_perm [1,1,1,1]
#define DPP_QUAD2 0xAA   // quad_perm [2,2,2,2]
#define DPP_QUAD3 0xFF   // quad_perm [3,3,3,3]
#define DPP_HALF_MIRROR 0x141

template <int CTRL>
__device__ __forceinline__ float dpp_mov(float v) {
    int r = __builtin_amdgcn_update_dpp(0, __float_as_int(v), CTRL, 0xF, 0xF, true);
    return __int_as_float(r);
}

__device__ __forceinline__ float tanh_fast(float a) {
    // tanh(a) = 1 - 2/(1+e^{2a});  e^{2a} = exp2(a * 2*log2(e))
    float e = __builtin_amdgcn_exp2f(a * 2.8853900817779268f);
    float r = __builtin_amdgcn_rcpf(e + 1.0f);
    return __builtin_fmaf(-2.0f, r, 1.0f);
}

__global__ __launch_bounds__(256, 1) void rnn_kernel(
    const float* __restrict__ x,    // [B, T, I]
    const float* __restrict__ Wih,  // [H, I]
    const float* __restrict__ Whh,  // [H, H]
    const float* __restrict__ bih,  // [H]
    const float* __restrict__ bhh,  // [H]
    const float* __restrict__ Wfc,  // [1, H]
    const float* __restrict__ bfc,  // [1]
    float* __restrict__ out)        // [B*T] out, then [B*H] hidden
{
    const int tid  = threadIdx.x;
    const int k    = tid & 7;                 // h-row owned by this lane (7=dummy)
    const int b    = blockIdx.x * 32 + (tid >> 3);
    const int quad = (tid >> 2) & 1;          // 0: lanes 0-3 of group, 1: lanes 4-7

    // ---- load-time weight permutation --------------------------------------
    // dot = sum_j wa[j]*a_j + wb[j]*b_j
    // quad0 lane (row k): a_j=h_j,     b_j=h_{4+j} -> wa[j]=W[k][j],   wb[j]=W[k][4+j] (wb3=0)
    // quad1 lane (row k): a_j=h_{4+j}, b_j=h_j     -> wa[j]=W[k][4+j] (wa3=0), wb[j]=W[k][j]
    float wih[7];
    float wa[4], wb[4], wfa[4], wfb[4];
    float bias = 0.0f;
    {
        float whh_row[8];
        #pragma unroll
        for (int i = 0; i < 8; ++i) whh_row[i] = 0.0f;
        if (k < 7) {
            #pragma unroll
            for (int i = 0; i < 7; ++i) {
                wih[i] = Wih[k * 7 + i];
                whh_row[i] = Whh[k * 7 + i];
            }
            bias = bih[k] + bhh[k];
        } else {
            #pragma unroll
            for (int i = 0; i < 7; ++i) wih[i] = 0.0f;
        }
        float wfc_row[8];
        #pragma unroll
        for (int j = 0; j < 7; ++j) wfc_row[j] = Wfc[j];
        wfc_row[7] = 0.0f;
        #pragma unroll
        for (int j = 0; j < 4; ++j) {
            wa[j]  = quad ? whh_row[4 + j] : whh_row[j];
            wb[j]  = quad ? whh_row[j]     : whh_row[4 + j];
            wfa[j] = quad ? wfc_row[4 + j] : wfc_row[j];
            wfb[j] = quad ? wfc_row[j]     : wfc_row[4 + j];
        }
    }
    const float bfcv = bfc[0];

    // x row: 512*7 = 3584 floats = 896 float4 per chain
    const float4* xrow = (const float4*)(x + (size_t)b * (T_STEPS * 7));
    float* outp = out + (size_t)b * T_STEPS;

    // h state lives as (a0..a3, b0..b3); h=0 initially
    float a0 = 0.f, a1 = 0.f, a2 = 0.f, a3 = 0.f;
    float b0 = 0.f, b1 = 0.f, b2 = 0.f, b3 = 0.f;

    float4 bufA[14], bufB[14];   // 8 steps * 7 inputs = 56 floats per chunk
    #pragma unroll
    for (int i = 0; i < 14; ++i) bufA[i] = xrow[i];

    auto process = [&](const float4 (&buf)[14], int c) {
        float xv[56];
        #pragma unroll
        for (int i = 0; i < 14; ++i) {   // register renaming only, no instrs
            xv[4 * i + 0] = buf[i].x; xv[4 * i + 1] = buf[i].y;
            xv[4 * i + 2] = buf[i].z; xv[4 * i + 3] = buf[i].w;
        }
        // Input projection for all 8 steps (independent of h -> pure ILP filler)
        float u[8];
        #pragma unroll
        for (int s = 0; s < 8; ++s) {
            const float* xs = &xv[s * 7];
            float p01 = __builtin_fmaf(wih[1], xs[1], wih[0] * xs[0]);
            float p23 = __builtin_fmaf(wih[3], xs[3], wih[2] * xs[2]);
            float p45 = __builtin_fmaf(wih[5], xs[5], wih[4] * xs[4]);
            float p6b = __builtin_fmaf(wih[6], xs[6], bias);
            u[s] = (p01 + p23) + (p45 + p6b);
        }
        float o[8];
        #pragma unroll
        for (int s = 0; s < 8; ++s) {
            // recurrent dot off (a,b) state, tree-reduced, u folded in early
            float p0 = __builtin_fmaf(wa[0], a0, u[s]);
            float p1 = __builtin_fmaf(wa[2], a2, wa[1] * a1);
            float p2 = __builtin_fmaf(wb[0], b0, wa[3] * a3);
            float p3 = __builtin_fmaf(wb[2], b2, wb[1] * b1);
            float p4 = wb[3] * b3;
            float acc = (p0 + p1) + (p2 + (p3 + p4));
            float hk = tanh_fast(acc);
            // DPP broadcast: new (a,b) state (VALU-rate, no LDS)
            a0 = dpp_mov<DPP_QUAD0>(hk);
            a1 = dpp_mov<DPP_QUAD1>(hk);
            a2 = dpp_mov<DPP_QUAD2>(hk);
            a3 = dpp_mov<DPP_QUAD3>(hk);
            b0 = dpp_mov<DPP_HALF_MIRROR>(a0);
            b1 = dpp_mov<DPP_HALF_MIRROR>(a1);
            b2 = dpp_mov<DPP_HALF_MIRROR>(a2);
            b3 = dpp_mov<DPP_HALF_MIRROR>(a3);
            // output projection off (a,b) — off the critical path
            float r0 = __builtin_fmaf(wfa[0], a0, bfcv);
            float r1 = __builtin_fmaf(wfa[2], a2, wfa[1] * a1);
            float r2 = __builtin_fmaf(wfb[1], b1, wfb[0] * b0);
            float r3 = __builtin_fmaf(wfb[3], b3, wfb[2] * b2);
            o[s] = (r0 + r1) + (r2 + r3);
        }
        if (k == 7) {
            *(float4*)(outp + c * 8 + 0) = make_float4(o[0], o[1], o[2], o[3]);
            *(float4*)(outp + c * 8 + 4) = make_float4(o[4], o[5], o[6], o[7]);
        }
    };

    for (int c = 0; c < 64; c += 2) {
        #pragma unroll
        for (int i = 0; i < 14; ++i) bufB[i] = xrow[(c + 1) * 14 + i];
        process(bufA, c);
        if (c + 2 < 64) {
            #pragma unroll
            for (int i = 0; i < 14; ++i) bufA[i] = xrow[(c + 2) * 14 + i];
        }
        process(bufB, c + 1);
    }

    // hidden state h_T: every lane holds full h in (a,b); lane k's own value
    // is a_{k&3} in both quads (quadA: h_k=a_k; quadB: h_{4+j}=a_j).
    if (k < 7) {
        int kk = k & 3;
        float hv = (kk == 0) ? a0 : (kk == 1) ? a1 : (kk == 2) ? a2 : a3;
        out[(size_t)B_TOTAL * T_STEPS + (size_t)b * 7 + k] = hv;
    }
}

extern "C" void kernel_launch(void* const* d_in, const int* in_sizes, int n_in,
                              void* d_out, int out_size, void* d_ws, size_t ws_size,
                              hipStream_t stream) {
    const float* x   = (const float*)d_in[0];
    const float* Wih = (const float*)d_in[1];
    const float* Whh = (const float*)d_in[2];
    const float* bih = (const float*)d_in[3];
    const float* bhh = (const float*)d_in[4];
    const float* Wfc = (const float*)d_in[5];
    const float* bfc = (const float*)d_in[6];
    float* out = (float*)d_out;

    // 8192 chains * 8 lanes = 65536 threads; 256/block -> 256 blocks (1/CU)
    rnn_kernel<<<dim3(B_TOTAL / 32), dim3(256), 0, stream>>>(
        x, Wih, Whh, bih, bhh, Wfc, bfc, out);
}